// Round 2
// baseline (140.647 us; speedup 1.0000x reference)
//
#include <hip/hip_runtime.h>
#include <math.h>

// Problem constants (from reference: B=1024, N=4096, fp32).
#define BATCH    1024
#define NPTS     4096
#define THREADS  256
#define WAVES    (THREADS / 64)
#define SPLITS   2                    // blocks per batch in stage 1
#define SLICE    (NPTS / SPLITS)      // 2048 floats per split
#define SLICE_V  (SLICE / 4)          // 512 float4 per split
#define ITERS    (SLICE_V / THREADS)  // 2 float4 iterations per thread
#define NACC     23
#define WS_STRIDE 24                  // padded partial-sum stride (floats)

// Accumulator layout (23 floats):
//  0      : sw        = sum w
//  1..3   : mw[i]     = sum m_i w
//  4..6   : yw[i]     = sum y_i w
//  7..12  : Mw sym    = (00,01,02,11,12,22)
// 13..21  : MY[i][j]  row-major
// 22      : yy        = sum (y.y) w

__global__ __launch_bounds__(THREADS) void locblock_stage1(
    const float* __restrict__ m,   // (B,3,N)
    const float* __restrict__ y,   // (B,3,N)
    const float* __restrict__ w,   // (B,1,N)
    float* __restrict__ ws)        // (B*SPLITS, WS_STRIDE) partial sums
{
    const int blk  = blockIdx.x;
    const int b    = blk >> 1;          // batch
    const int s    = blk & 1;           // split
    const int tid  = threadIdx.x;
    const int lane = tid & 63;
    const int wave = tid >> 6;

    const size_t mb  = (size_t)b * 3 * NPTS;
    const int    off = s * SLICE;       // float offset within a row
    const float4* m0p = (const float4*)(m + mb + 0 * NPTS + off);
    const float4* m1p = (const float4*)(m + mb + 1 * NPTS + off);
    const float4* m2p = (const float4*)(m + mb + 2 * NPTS + off);
    const float4* y0p = (const float4*)(y + mb + 0 * NPTS + off);
    const float4* y1p = (const float4*)(y + mb + 1 * NPTS + off);
    const float4* y2p = (const float4*)(y + mb + 2 * NPTS + off);
    const float4* wp  = (const float4*)(w + (size_t)b * NPTS + off);

    float acc[NACC];
#pragma unroll
    for (int i = 0; i < NACC; ++i) acc[i] = 0.f;

    auto accum = [&](float wv, float m0v, float m1v, float m2v,
                     float y0v, float y1v, float y2v) {
        float wm0 = wv * m0v, wm1 = wv * m1v, wm2 = wv * m2v;
        acc[0]  += wv;
        acc[1]  += wm0;        acc[2]  += wm1;        acc[3]  += wm2;
        acc[4]  += wv * y0v;   acc[5]  += wv * y1v;   acc[6]  += wv * y2v;
        acc[7]  += wm0 * m0v;  acc[8]  += wm0 * m1v;  acc[9]  += wm0 * m2v;
        acc[10] += wm1 * m1v;  acc[11] += wm1 * m2v;  acc[12] += wm2 * m2v;
        acc[13] += wm0 * y0v;  acc[14] += wm0 * y1v;  acc[15] += wm0 * y2v;
        acc[16] += wm1 * y0v;  acc[17] += wm1 * y1v;  acc[18] += wm1 * y2v;
        acc[19] += wm2 * y0v;  acc[20] += wm2 * y1v;  acc[21] += wm2 * y2v;
        acc[22] += wv * (y0v * y0v + y1v * y1v + y2v * y2v);
    };

    // Load all ITERS*7 float4s up front (independent vmem), then accumulate.
    float4 M0[ITERS], M1[ITERS], M2[ITERS], Y0[ITERS], Y1[ITERS], Y2[ITERS], W[ITERS];
#pragma unroll
    for (int it = 0; it < ITERS; ++it) {
        const int v = it * THREADS + tid;
        M0[it] = m0p[v]; M1[it] = m1p[v]; M2[it] = m2p[v];
        Y0[it] = y0p[v]; Y1[it] = y1p[v]; Y2[it] = y2p[v];
        W[it]  = wp[v];
    }
#pragma unroll
    for (int it = 0; it < ITERS; ++it) {
        accum(W[it].x, M0[it].x, M1[it].x, M2[it].x, Y0[it].x, Y1[it].x, Y2[it].x);
        accum(W[it].y, M0[it].y, M1[it].y, M2[it].y, Y0[it].y, Y1[it].y, Y2[it].y);
        accum(W[it].z, M0[it].z, M1[it].z, M2[it].z, Y0[it].z, Y1[it].z, Y2[it].z);
        accum(W[it].w, M0[it].w, M1[it].w, M2[it].w, Y0[it].w, Y1[it].w, Y2[it].w);
    }

    // Wave-level butterfly reduction (64 lanes) for each accumulator.
#pragma unroll
    for (int i = 0; i < NACC; ++i) {
        float v = acc[i];
        v += __shfl_xor(v, 32, 64);
        v += __shfl_xor(v, 16, 64);
        v += __shfl_xor(v, 8, 64);
        v += __shfl_xor(v, 4, 64);
        v += __shfl_xor(v, 2, 64);
        v += __shfl_xor(v, 1, 64);
        acc[i] = v;
    }

    __shared__ float partial[WAVES][NACC];
    if (lane == 0) {
#pragma unroll
        for (int i = 0; i < NACC; ++i) partial[wave][i] = acc[i];
    }
    __syncthreads();
    if (tid < NACC) {
        ws[(size_t)blk * WS_STRIDE + tid] =
            partial[0][tid] + partial[1][tid] + partial[2][tid] + partial[3][tid];
    }
}

__global__ __launch_bounds__(THREADS) void locblock_stage2(
    const float* __restrict__ ws,  // (B*SPLITS, WS_STRIDE)
    float* __restrict__ out)       // Qn (B*169) | scales (B) | offsets (B)
{
    const int b    = blockIdx.x;
    const int tid  = threadIdx.x;
    const int lane = tid & 63;
    const int wave = tid >> 6;

    __shared__ float sums[NACC];
    __shared__ float red[WAVES];
    __shared__ float scale_s;

    if (tid < NACC) {
        float v = 0.f;
#pragma unroll
        for (int s = 0; s < SPLITS; ++s)
            v += ws[(size_t)(b * SPLITS + s) * WS_STRIDE + tid];
        sums[tid] = v;
    }
    __syncthreads();

    // Assemble one Q entry per thread (169 entries of a 13x13).
    float qv = 0.f;
    if (tid < 169) {
        const int r = tid / 13, c = tid % 13;
        const float* mwv = &sums[1];
        const float* ywv = &sums[4];
        auto Mwf = [&](int i, int j) -> float {
            if (i > j) { int t = i; i = j; j = t; }
            int idx = (i == 0) ? j : ((i == 1) ? (j + 2) : 5);
            return sums[7 + idx];
        };
        auto MYf = [&](int i, int j) -> float { return sums[13 + i * 3 + j]; };

        if (r == 0) {
            if (c == 0)            qv = 0.f;
            else if (c <= 9)       qv = -MYf((c - 1) / 3, (c - 1) % 3);   // Qch
            else                   qv = ywv[c - 10];
        } else if (c == 0) {
            if (r <= 9)            qv = -MYf((r - 1) / 3, (r - 1) % 3);   // Qch
            else                   qv = ywv[r - 10];
        } else if (r <= 9 && c <= 9) {                                    // Qcc
            int a = r - 1, d = c - 1;
            int i = a / 3, k = a % 3, j = d / 3, l = d % 3;
            qv = (k == l) ? Mwf(i, j) : 0.f;
        } else if (r <= 9) {                                              // Qct
            int a = r - 1, i = a / 3, k = a % 3, l = c - 10;
            qv = (k == l) ? -mwv[i] : 0.f;
        } else if (c <= 9) {                                              // Qct^T
            int a = c - 1, i = a / 3, k = a % 3, l = r - 10;
            qv = (k == l) ? -mwv[i] : 0.f;
        } else {                                                          // Qtt
            qv = (r == c) ? sums[0] : 0.f;
        }
    }

    // Block-wide sum of squares -> scale.
    float sq = (tid < 169) ? qv * qv : 0.f;
    sq += __shfl_xor(sq, 32, 64);
    sq += __shfl_xor(sq, 16, 64);
    sq += __shfl_xor(sq, 8, 64);
    sq += __shfl_xor(sq, 4, 64);
    sq += __shfl_xor(sq, 2, 64);
    sq += __shfl_xor(sq, 1, 64);
    if (lane == 0) red[wave] = sq;
    __syncthreads();
    if (tid == 0) {
        scale_s = sqrtf(red[0] + red[1] + red[2] + red[3]);
    }
    __syncthreads();

    const float inv_scale = 1.0f / scale_s;
    if (tid < 169) {
        out[(size_t)b * 169 + tid] = qv * inv_scale;
    }
    if (tid == 0) {
        out[(size_t)BATCH * 169 + b]         = scale_s;   // scales
        out[(size_t)BATCH * 169 + BATCH + b] = sums[22];  // offsets (yy)
    }
}

extern "C" void kernel_launch(void* const* d_in, const int* in_sizes, int n_in,
                              void* d_out, int out_size, void* d_ws, size_t ws_size,
                              hipStream_t stream) {
    const float* m = (const float*)d_in[0];  // keypoints_3D_src (B,3,N)
    const float* y = (const float*)d_in[1];  // keypoints_3D_trg (B,3,N)
    const float* w = (const float*)d_in[2];  // weights (B,1,N)
    float* out = (float*)d_out;
    float* ws  = (float*)d_ws;               // needs B*SPLITS*WS_STRIDE*4 = 192 KiB

    locblock_stage1<<<BATCH * SPLITS, THREADS, 0, stream>>>(m, y, w, ws);
    locblock_stage2<<<BATCH, THREADS, 0, stream>>>(ws, out);
}

// Round 4
// 137.806 us; speedup vs baseline: 1.0206x; 1.0206x over previous
//
#include <hip/hip_runtime.h>
#include <math.h>

// Problem constants (from reference: B=1024, N=4096, fp32).
#define BATCH    1024
#define NPTS     4096
#define THREADS  256
#define WAVES    (THREADS / 64)
#define SPLITS   2                    // blocks per batch in stage 1
#define SLICE    (NPTS / SPLITS)      // 2048 floats per split
#define SLICE_V  (SLICE / 4)          // 512 float4 per split
#define ITERS    (SLICE_V / THREADS)  // 2 float4 iterations per thread
#define NACC     23
#define WS_STRIDE 24                  // padded partial-sum stride (floats)

// Native clang vector type — __builtin_nontemporal_load requires a pointer to
// scalar/vector-of-scalar, not HIP's float4 struct.
typedef float fx4 __attribute__((ext_vector_type(4)));

// Accumulator layout (23 floats):
//  0      : sw        = sum w
//  1..3   : mw[i]     = sum m_i w
//  4..6   : yw[i]     = sum y_i w
//  7..12  : Mw sym    = (00,01,02,11,12,22)
// 13..21  : MY[i][j]  row-major
// 22      : yy        = sum (y.y) w

// Inputs have zero reuse (each byte read once by one block) — bypass L2/L3
// with non-temporal loads so reads stream from HBM instead of thrashing the
// half-resident Infinity Cache (R2 evidence: 2.8 TB/s effective ceiling).
__device__ inline fx4 nt_load4(const float* p) {
    return __builtin_nontemporal_load((const fx4*)p);
}

__global__ __launch_bounds__(THREADS) void locblock_stage1(
    const float* __restrict__ m,   // (B,3,N)
    const float* __restrict__ y,   // (B,3,N)
    const float* __restrict__ w,   // (B,1,N)
    float* __restrict__ ws)        // (B*SPLITS, WS_STRIDE) partial sums
{
    const int blk  = blockIdx.x;
    const int b    = blk >> 1;          // batch
    const int s    = blk & 1;           // split
    const int tid  = threadIdx.x;
    const int lane = tid & 63;
    const int wave = tid >> 6;

    const size_t mb  = (size_t)b * 3 * NPTS;
    const int    off = s * SLICE;       // float offset within a row
    const float* m0p = m + mb + 0 * NPTS + off;
    const float* m1p = m + mb + 1 * NPTS + off;
    const float* m2p = m + mb + 2 * NPTS + off;
    const float* y0p = y + mb + 0 * NPTS + off;
    const float* y1p = y + mb + 1 * NPTS + off;
    const float* y2p = y + mb + 2 * NPTS + off;
    const float* wp  = w + (size_t)b * NPTS + off;

    float acc[NACC];
#pragma unroll
    for (int i = 0; i < NACC; ++i) acc[i] = 0.f;

    auto accum = [&](float wv, float m0v, float m1v, float m2v,
                     float y0v, float y1v, float y2v) {
        float wm0 = wv * m0v, wm1 = wv * m1v, wm2 = wv * m2v;
        acc[0]  += wv;
        acc[1]  += wm0;        acc[2]  += wm1;        acc[3]  += wm2;
        acc[4]  += wv * y0v;   acc[5]  += wv * y1v;   acc[6]  += wv * y2v;
        acc[7]  += wm0 * m0v;  acc[8]  += wm0 * m1v;  acc[9]  += wm0 * m2v;
        acc[10] += wm1 * m1v;  acc[11] += wm1 * m2v;  acc[12] += wm2 * m2v;
        acc[13] += wm0 * y0v;  acc[14] += wm0 * y1v;  acc[15] += wm0 * y2v;
        acc[16] += wm1 * y0v;  acc[17] += wm1 * y1v;  acc[18] += wm1 * y2v;
        acc[19] += wm2 * y0v;  acc[20] += wm2 * y1v;  acc[21] += wm2 * y2v;
        acc[22] += wv * (y0v * y0v + y1v * y1v + y2v * y2v);
    };

    // Load all ITERS*7 vectors up front (independent vmem), then accumulate.
    fx4 M0[ITERS], M1[ITERS], M2[ITERS], Y0[ITERS], Y1[ITERS], Y2[ITERS], W[ITERS];
#pragma unroll
    for (int it = 0; it < ITERS; ++it) {
        const int v = (it * THREADS + tid) * 4;
        M0[it] = nt_load4(m0p + v); M1[it] = nt_load4(m1p + v); M2[it] = nt_load4(m2p + v);
        Y0[it] = nt_load4(y0p + v); Y1[it] = nt_load4(y1p + v); Y2[it] = nt_load4(y2p + v);
        W[it]  = nt_load4(wp + v);
    }
#pragma unroll
    for (int it = 0; it < ITERS; ++it) {
#pragma unroll
        for (int e = 0; e < 4; ++e) {
            accum(W[it][e], M0[it][e], M1[it][e], M2[it][e],
                  Y0[it][e], Y1[it][e], Y2[it][e]);
        }
    }

    // Wave-level butterfly reduction (64 lanes) for each accumulator.
#pragma unroll
    for (int i = 0; i < NACC; ++i) {
        float v = acc[i];
        v += __shfl_xor(v, 32, 64);
        v += __shfl_xor(v, 16, 64);
        v += __shfl_xor(v, 8, 64);
        v += __shfl_xor(v, 4, 64);
        v += __shfl_xor(v, 2, 64);
        v += __shfl_xor(v, 1, 64);
        acc[i] = v;
    }

    __shared__ float partial[WAVES][NACC];
    if (lane == 0) {
#pragma unroll
        for (int i = 0; i < NACC; ++i) partial[wave][i] = acc[i];
    }
    __syncthreads();
    if (tid < NACC) {
        ws[(size_t)blk * WS_STRIDE + tid] =
            partial[0][tid] + partial[1][tid] + partial[2][tid] + partial[3][tid];
    }
}

__global__ __launch_bounds__(THREADS) void locblock_stage2(
    const float* __restrict__ ws,  // (B*SPLITS, WS_STRIDE)
    float* __restrict__ out)       // Qn (B*169) | scales (B) | offsets (B)
{
    const int b    = blockIdx.x;
    const int tid  = threadIdx.x;
    const int lane = tid & 63;
    const int wave = tid >> 6;

    __shared__ float sums[NACC];
    __shared__ float red[WAVES];
    __shared__ float scale_s;

    if (tid < NACC) {
        float v = 0.f;
#pragma unroll
        for (int s = 0; s < SPLITS; ++s)
            v += ws[(size_t)(b * SPLITS + s) * WS_STRIDE + tid];
        sums[tid] = v;
    }
    __syncthreads();

    // Assemble one Q entry per thread (169 entries of a 13x13).
    float qv = 0.f;
    if (tid < 169) {
        const int r = tid / 13, c = tid % 13;
        const float* mwv = &sums[1];
        const float* ywv = &sums[4];
        auto Mwf = [&](int i, int j) -> float {
            if (i > j) { int t = i; i = j; j = t; }
            int idx = (i == 0) ? j : ((i == 1) ? (j + 2) : 5);
            return sums[7 + idx];
        };
        auto MYf = [&](int i, int j) -> float { return sums[13 + i * 3 + j]; };

        if (r == 0) {
            if (c == 0)            qv = 0.f;
            else if (c <= 9)       qv = -MYf((c - 1) / 3, (c - 1) % 3);   // Qch
            else                   qv = ywv[c - 10];
        } else if (c == 0) {
            if (r <= 9)            qv = -MYf((r - 1) / 3, (r - 1) % 3);   // Qch
            else                   qv = ywv[r - 10];
        } else if (r <= 9 && c <= 9) {                                    // Qcc
            int a = r - 1, d = c - 1;
            int i = a / 3, k = a % 3, j = d / 3, l = d % 3;
            qv = (k == l) ? Mwf(i, j) : 0.f;
        } else if (r <= 9) {                                              // Qct
            int a = r - 1, i = a / 3, k = a % 3, l = c - 10;
            qv = (k == l) ? -mwv[i] : 0.f;
        } else if (c <= 9) {                                              // Qct^T
            int a = c - 1, i = a / 3, k = a % 3, l = r - 10;
            qv = (k == l) ? -mwv[i] : 0.f;
        } else {                                                          // Qtt
            qv = (r == c) ? sums[0] : 0.f;
        }
    }

    // Block-wide sum of squares -> scale.
    float sq = (tid < 169) ? qv * qv : 0.f;
    sq += __shfl_xor(sq, 32, 64);
    sq += __shfl_xor(sq, 16, 64);
    sq += __shfl_xor(sq, 8, 64);
    sq += __shfl_xor(sq, 4, 64);
    sq += __shfl_xor(sq, 2, 64);
    sq += __shfl_xor(sq, 1, 64);
    if (lane == 0) red[wave] = sq;
    __syncthreads();
    if (tid == 0) {
        scale_s = sqrtf(red[0] + red[1] + red[2] + red[3]);
    }
    __syncthreads();

    const float inv_scale = 1.0f / scale_s;
    if (tid < 169) {
        out[(size_t)b * 169 + tid] = qv * inv_scale;
    }
    if (tid == 0) {
        out[(size_t)BATCH * 169 + b]         = scale_s;   // scales
        out[(size_t)BATCH * 169 + BATCH + b] = sums[22];  // offsets (yy)
    }
}

extern "C" void kernel_launch(void* const* d_in, const int* in_sizes, int n_in,
                              void* d_out, int out_size, void* d_ws, size_t ws_size,
                              hipStream_t stream) {
    const float* m = (const float*)d_in[0];  // keypoints_3D_src (B,3,N)
    const float* y = (const float*)d_in[1];  // keypoints_3D_trg (B,3,N)
    const float* w = (const float*)d_in[2];  // weights (B,1,N)
    float* out = (float*)d_out;
    float* ws  = (float*)d_ws;               // needs B*SPLITS*WS_STRIDE*4 = 192 KiB

    locblock_stage1<<<BATCH * SPLITS, THREADS, 0, stream>>>(m, y, w, ws);
    locblock_stage2<<<BATCH, THREADS, 0, stream>>>(ws, out);
}

// Round 5
// 137.637 us; speedup vs baseline: 1.0219x; 1.0012x over previous
//
#include <hip/hip_runtime.h>
#include <math.h>

// Problem constants (from reference: B=1024, N=4096, fp32).
#define BATCH    1024
#define NPTS     4096
#define THREADS  256
#define WAVES    (THREADS / 64)
#define NV       (NPTS / 4)          // float4 per row = 1024
#define ITERS    (NV / THREADS)      // 4 float4 iterations per thread
#define NACC     23
#define RPAD     264                 // LDS row stride (256 + 8): conflict-free

typedef float fx4 __attribute__((ext_vector_type(4)));

// Accumulator layout (23 floats):
//  0      : sw        = sum w
//  1..3   : mw[i]     = sum m_i w
//  4..6   : yw[i]     = sum y_i w
//  7..12  : Mw sym    = (00,01,02,11,12,22)
// 13..21  : MY[i][j]  row-major
// 22      : yy        = sum (y.y) w

// R4 evidence: duration is memory-source-invariant (L3-hit replays == cold
// HBM == NT-bypass). Limiter was VGPR starvation (40 regs -> loads issued in
// batches of ~2 with waits) + 552 dependent ds_swizzle per block. This version:
// launch_bounds(256,3) for ~168 VGPR budget, all 28 loads preloaded (112 VGPR
// payload in flight), LDS fold -> single-wave butterfly, fused epilogue.
__global__ __launch_bounds__(THREADS, 3) void locblock_fused(
    const float* __restrict__ m,   // (B,3,N)
    const float* __restrict__ y,   // (B,3,N)
    const float* __restrict__ w,   // (B,1,N)
    float* __restrict__ out)       // Qn (B*169) | scales (B) | offsets (B)
{
    const int b    = blockIdx.x;
    const int tid  = threadIdx.x;
    const int lane = tid & 63;
    const int wave = tid >> 6;

    const size_t mb = (size_t)b * 3 * NPTS;
    const float* m0p = m + mb + 0 * NPTS;
    const float* m1p = m + mb + 1 * NPTS;
    const float* m2p = m + mb + 2 * NPTS;
    const float* y0p = y + mb + 0 * NPTS;
    const float* y1p = y + mb + 1 * NPTS;
    const float* y2p = y + mb + 2 * NPTS;
    const float* wp  = w + (size_t)b * NPTS;

    // Preload ALL 28 float4s up front — 112 VGPRs of payload in flight.
    fx4 M0[ITERS], M1[ITERS], M2[ITERS], Y0[ITERS], Y1[ITERS], Y2[ITERS], W[ITERS];
#pragma unroll
    for (int it = 0; it < ITERS; ++it) {
        const int v = (it * THREADS + tid) * 4;
        M0[it] = *(const fx4*)(m0p + v);
        M1[it] = *(const fx4*)(m1p + v);
        M2[it] = *(const fx4*)(m2p + v);
        Y0[it] = *(const fx4*)(y0p + v);
        Y1[it] = *(const fx4*)(y1p + v);
        Y2[it] = *(const fx4*)(y2p + v);
        W[it]  = *(const fx4*)(wp  + v);
    }

    float acc[NACC];
#pragma unroll
    for (int i = 0; i < NACC; ++i) acc[i] = 0.f;

    auto accum = [&](float wv, float m0v, float m1v, float m2v,
                     float y0v, float y1v, float y2v) {
        float wm0 = wv * m0v, wm1 = wv * m1v, wm2 = wv * m2v;
        acc[0]  += wv;
        acc[1]  += wm0;        acc[2]  += wm1;        acc[3]  += wm2;
        acc[4]  += wv * y0v;   acc[5]  += wv * y1v;   acc[6]  += wv * y2v;
        acc[7]  += wm0 * m0v;  acc[8]  += wm0 * m1v;  acc[9]  += wm0 * m2v;
        acc[10] += wm1 * m1v;  acc[11] += wm1 * m2v;  acc[12] += wm2 * m2v;
        acc[13] += wm0 * y0v;  acc[14] += wm0 * y1v;  acc[15] += wm0 * y2v;
        acc[16] += wm1 * y0v;  acc[17] += wm1 * y1v;  acc[18] += wm1 * y2v;
        acc[19] += wm2 * y0v;  acc[20] += wm2 * y1v;  acc[21] += wm2 * y2v;
        acc[22] += wv * (y0v * y0v + y1v * y1v + y2v * y2v);
    };

#pragma unroll
    for (int it = 0; it < ITERS; ++it) {
#pragma unroll
        for (int e = 0; e < 4; ++e) {
            accum(W[it][e], M0[it][e], M1[it][e], M2[it][e],
                  Y0[it][e], Y1[it][e], Y2[it][e]);
        }
    }

    // ---- Reduction: LDS fold (256 threads -> 64 lanes) + wave-0 butterfly ----
    // acc-major layout, row stride 264 (264 % 32 == 8): writes (fixed i, lanes
    // contiguous) and fold reads (lane + 64k) are both bank-conflict-free.
    __shared__ float red_lds[NACC * RPAD];
    __shared__ float sums[NACC];
    __shared__ float sqred[WAVES];
    __shared__ float scale_s;

#pragma unroll
    for (int i = 0; i < NACC; ++i) red_lds[i * RPAD + tid] = acc[i];
    __syncthreads();

    if (wave == 0) {
        float part[NACC];
#pragma unroll
        for (int i = 0; i < NACC; ++i) {
            const float* row = &red_lds[i * RPAD + lane];
            part[i] = row[0] + row[64] + row[128] + row[192];
        }
        // Single-wave butterfly across 64 lanes.
#pragma unroll
        for (int i = 0; i < NACC; ++i) {
            float v = part[i];
            v += __shfl_xor(v, 32, 64);
            v += __shfl_xor(v, 16, 64);
            v += __shfl_xor(v, 8, 64);
            v += __shfl_xor(v, 4, 64);
            v += __shfl_xor(v, 2, 64);
            v += __shfl_xor(v, 1, 64);
            part[i] = v;
        }
        if (lane == 0) {
#pragma unroll
            for (int i = 0; i < NACC; ++i) sums[i] = part[i];
        }
    }
    __syncthreads();

    // ---- Epilogue: assemble Q (one entry per thread), normalize, store ----
    float qv = 0.f;
    if (tid < 169) {
        const int r = tid / 13, c = tid % 13;
        const float* mwv = &sums[1];
        const float* ywv = &sums[4];
        auto Mwf = [&](int i, int j) -> float {
            if (i > j) { int t = i; i = j; j = t; }
            int idx = (i == 0) ? j : ((i == 1) ? (j + 2) : 5);
            return sums[7 + idx];
        };
        auto MYf = [&](int i, int j) -> float { return sums[13 + i * 3 + j]; };

        if (r == 0) {
            if (c == 0)            qv = 0.f;
            else if (c <= 9)       qv = -MYf((c - 1) / 3, (c - 1) % 3);   // Qch
            else                   qv = ywv[c - 10];
        } else if (c == 0) {
            if (r <= 9)            qv = -MYf((r - 1) / 3, (r - 1) % 3);   // Qch
            else                   qv = ywv[r - 10];
        } else if (r <= 9 && c <= 9) {                                    // Qcc
            int a = r - 1, d = c - 1;
            int i = a / 3, k = a % 3, j = d / 3, l = d % 3;
            qv = (k == l) ? Mwf(i, j) : 0.f;
        } else if (r <= 9) {                                              // Qct
            int a = r - 1, i = a / 3, k = a % 3, l = c - 10;
            qv = (k == l) ? -mwv[i] : 0.f;
        } else if (c <= 9) {                                              // Qct^T
            int a = c - 1, i = a / 3, k = a % 3, l = r - 10;
            qv = (k == l) ? -mwv[i] : 0.f;
        } else {                                                          // Qtt
            qv = (r == c) ? sums[0] : 0.f;
        }
    }

    // Block-wide sum of squares -> scale.
    float sq = (tid < 169) ? qv * qv : 0.f;
    sq += __shfl_xor(sq, 32, 64);
    sq += __shfl_xor(sq, 16, 64);
    sq += __shfl_xor(sq, 8, 64);
    sq += __shfl_xor(sq, 4, 64);
    sq += __shfl_xor(sq, 2, 64);
    sq += __shfl_xor(sq, 1, 64);
    if (lane == 0) sqred[wave] = sq;
    __syncthreads();
    if (tid == 0) {
        scale_s = sqrtf(sqred[0] + sqred[1] + sqred[2] + sqred[3]);
    }
    __syncthreads();

    const float inv_scale = 1.0f / scale_s;
    if (tid < 169) {
        out[(size_t)b * 169 + tid] = qv * inv_scale;
    }
    if (tid == 0) {
        out[(size_t)BATCH * 169 + b]         = scale_s;   // scales
        out[(size_t)BATCH * 169 + BATCH + b] = sums[22];  // offsets (yy)
    }
}

extern "C" void kernel_launch(void* const* d_in, const int* in_sizes, int n_in,
                              void* d_out, int out_size, void* d_ws, size_t ws_size,
                              hipStream_t stream) {
    const float* m = (const float*)d_in[0];  // keypoints_3D_src (B,3,N)
    const float* y = (const float*)d_in[1];  // keypoints_3D_trg (B,3,N)
    const float* w = (const float*)d_in[2];  // weights (B,1,N)
    float* out = (float*)d_out;
    locblock_fused<<<BATCH, THREADS, 0, stream>>>(m, y, w, out);
}

// Round 6
// 137.187 us; speedup vs baseline: 1.0252x; 1.0033x over previous
//
#include <hip/hip_runtime.h>
#include <math.h>

// Problem constants (from reference: B=1024, N=4096, fp32).
#define BATCH    1024
#define NPTS     4096
#define THREADS  256
#define WAVES    4
#define HALF     (NPTS / 2)        // 2048 floats per stream-half
#define NSTREAM  7                 // m0,m1,m2,y0,y1,y2,w
#define CHUNKS   8                 // 1 KB chunks per stream-half (8 x 256 floats)
#define NACC     23
#define RPAD     264               // reduction row stride (256+8): conflict-free

typedef float fx4 __attribute__((ext_vector_type(4)));

// Accumulator layout (23 floats):
//  0      : sw        = sum w
//  1..3   : mw[i]     = sum m_i w
//  4..6   : yw[i]     = sum y_i w
//  7..12  : Mw sym    = (00,01,02,11,12,22)
// 13..21  : MY[i][j]  row-major
// 22     : yy        = sum (y.y) w

// R5 evidence: compiler sinks register preloads (VGPR=48), capping in-flight
// bytes/wave at ~3 KB -> vmem pipe 90% idle, 2.8 TB/s effective. Fix: async
// global->LDS staging (zero VGPR cost, deep vmcnt queue). 56 KB buffer, two
// sequential halves per block; 2 blocks/CU overlap load/compute; 512 resident
// blocks sweep memory in 2 generations.
__global__ __launch_bounds__(THREADS) void locblock_fused(
    const float* __restrict__ m,   // (B,3,N)
    const float* __restrict__ y,   // (B,3,N)
    const float* __restrict__ w,   // (B,1,N)
    float* __restrict__ out)       // Qn (B*169) | scales (B) | offsets (B)
{
    const int b    = blockIdx.x;
    const int tid  = threadIdx.x;
    const int lane = tid & 63;
    const int wave = tid >> 6;

    const size_t mb = (size_t)b * 3 * NPTS;
    const float* rows[NSTREAM] = {
        m + mb + 0 * NPTS, m + mb + 1 * NPTS, m + mb + 2 * NPTS,
        y + mb + 0 * NPTS, y + mb + 1 * NPTS, y + mb + 2 * NPTS,
        w + (size_t)b * NPTS
    };

    // Staging buffer: 7 streams x 2048 floats = 14336 floats = 56 KB.
    // Reused for the cross-wave reduction afterwards (needs 23*264 = 6072).
    __shared__ float smem[NSTREAM * HALF];
    __shared__ float sums[NACC];
    __shared__ float sqred[WAVES];
    __shared__ float scale_s;

    float acc[NACC];
#pragma unroll
    for (int i = 0; i < NACC; ++i) acc[i] = 0.f;

    auto accum = [&](float wv, float m0v, float m1v, float m2v,
                     float y0v, float y1v, float y2v) {
        float wm0 = wv * m0v, wm1 = wv * m1v, wm2 = wv * m2v;
        acc[0]  += wv;
        acc[1]  += wm0;        acc[2]  += wm1;        acc[3]  += wm2;
        acc[4]  += wv * y0v;   acc[5]  += wv * y1v;   acc[6]  += wv * y2v;
        acc[7]  += wm0 * m0v;  acc[8]  += wm0 * m1v;  acc[9]  += wm0 * m2v;
        acc[10] += wm1 * m1v;  acc[11] += wm1 * m2v;  acc[12] += wm2 * m2v;
        acc[13] += wm0 * y0v;  acc[14] += wm0 * y1v;  acc[15] += wm0 * y2v;
        acc[16] += wm1 * y0v;  acc[17] += wm1 * y1v;  acc[18] += wm1 * y2v;
        acc[19] += wm2 * y0v;  acc[20] += wm2 * y1v;  acc[21] += wm2 * y2v;
        acc[22] += wv * (y0v * y0v + y1v * y1v + y2v * y2v);
    };

    for (int h = 0; h < 2; ++h) {
        // ---- Async stage: each wave issues 14 x 1KB global->LDS copies ----
        // Chunk c of stream s: global = rows[s] + h*HALF + c*256 + lane*4,
        // LDS dest = smem + s*HALF + c*256 (+ lane*16B by HW).
#pragma unroll
        for (int s = 0; s < NSTREAM; ++s) {
#pragma unroll
            for (int k = 0; k < 2; ++k) {
                const int c = wave * 2 + k;
                const float* g = rows[s] + h * HALF + c * 256 + lane * 4;
                float* l = &smem[s * HALF + c * 256];
                __builtin_amdgcn_global_load_lds(
                    (__attribute__((address_space(1))) void*)(float*)g,
                    (__attribute__((address_space(3))) void*)l,
                    16, 0, 0);
            }
        }
        __syncthreads();   // compiler emits s_waitcnt vmcnt(0) before s_barrier

        // ---- Consume from LDS: 2 fx4 per stream per thread ----
#pragma unroll
        for (int k = 0; k < 2; ++k) {
            const int idx = (k * THREADS + tid) * 4;   // float offset in half
            fx4 vm0 = *(const fx4*)&smem[0 * HALF + idx];
            fx4 vm1 = *(const fx4*)&smem[1 * HALF + idx];
            fx4 vm2 = *(const fx4*)&smem[2 * HALF + idx];
            fx4 vy0 = *(const fx4*)&smem[3 * HALF + idx];
            fx4 vy1 = *(const fx4*)&smem[4 * HALF + idx];
            fx4 vy2 = *(const fx4*)&smem[5 * HALF + idx];
            fx4 vw  = *(const fx4*)&smem[6 * HALF + idx];
#pragma unroll
            for (int e = 0; e < 4; ++e) {
                accum(vw[e], vm0[e], vm1[e], vm2[e], vy0[e], vy1[e], vy2[e]);
            }
        }
        __syncthreads();   // buffer reused next half / reduction
    }

    // ---- Reduction: LDS fold (256 -> 64 lanes) + wave-0 butterfly ----
    // acc-major, row stride 264 (264 % 32 == 8): conflict-free writes/reads.
#pragma unroll
    for (int i = 0; i < NACC; ++i) smem[i * RPAD + tid] = acc[i];
    __syncthreads();

    if (wave == 0) {
        float part[NACC];
#pragma unroll
        for (int i = 0; i < NACC; ++i) {
            const float* row = &smem[i * RPAD + lane];
            part[i] = row[0] + row[64] + row[128] + row[192];
        }
#pragma unroll
        for (int i = 0; i < NACC; ++i) {
            float v = part[i];
            v += __shfl_xor(v, 32, 64);
            v += __shfl_xor(v, 16, 64);
            v += __shfl_xor(v, 8, 64);
            v += __shfl_xor(v, 4, 64);
            v += __shfl_xor(v, 2, 64);
            v += __shfl_xor(v, 1, 64);
            part[i] = v;
        }
        if (lane == 0) {
#pragma unroll
            for (int i = 0; i < NACC; ++i) sums[i] = part[i];
        }
    }
    __syncthreads();

    // ---- Epilogue: assemble Q (one entry per thread), normalize, store ----
    float qv = 0.f;
    if (tid < 169) {
        const int r = tid / 13, c = tid % 13;
        const float* mwv = &sums[1];
        const float* ywv = &sums[4];
        auto Mwf = [&](int i, int j) -> float {
            if (i > j) { int t = i; i = j; j = t; }
            int idx = (i == 0) ? j : ((i == 1) ? (j + 2) : 5);
            return sums[7 + idx];
        };
        auto MYf = [&](int i, int j) -> float { return sums[13 + i * 3 + j]; };

        if (r == 0) {
            if (c == 0)            qv = 0.f;
            else if (c <= 9)       qv = -MYf((c - 1) / 3, (c - 1) % 3);   // Qch
            else                   qv = ywv[c - 10];
        } else if (c == 0) {
            if (r <= 9)            qv = -MYf((r - 1) / 3, (r - 1) % 3);   // Qch
            else                   qv = ywv[r - 10];
        } else if (r <= 9 && c <= 9) {                                    // Qcc
            int a = r - 1, d = c - 1;
            int i = a / 3, k = a % 3, j = d / 3, l = d % 3;
            qv = (k == l) ? Mwf(i, j) : 0.f;
        } else if (r <= 9) {                                              // Qct
            int a = r - 1, i = a / 3, k = a % 3, l = c - 10;
            qv = (k == l) ? -mwv[i] : 0.f;
        } else if (c <= 9) {                                              // Qct^T
            int a = c - 1, i = a / 3, k = a % 3, l = r - 10;
            qv = (k == l) ? -mwv[i] : 0.f;
        } else {                                                          // Qtt
            qv = (r == c) ? sums[0] : 0.f;
        }
    }

    // Block-wide sum of squares -> scale.
    float sq = (tid < 169) ? qv * qv : 0.f;
    sq += __shfl_xor(sq, 32, 64);
    sq += __shfl_xor(sq, 16, 64);
    sq += __shfl_xor(sq, 8, 64);
    sq += __shfl_xor(sq, 4, 64);
    sq += __shfl_xor(sq, 2, 64);
    sq += __shfl_xor(sq, 1, 64);
    if (lane == 0) sqred[wave] = sq;
    __syncthreads();
    if (tid == 0) {
        scale_s = sqrtf(sqred[0] + sqred[1] + sqred[2] + sqred[3]);
    }
    __syncthreads();

    const float inv_scale = 1.0f / scale_s;
    if (tid < 169) {
        out[(size_t)b * 169 + tid] = qv * inv_scale;
    }
    if (tid == 0) {
        out[(size_t)BATCH * 169 + b]         = scale_s;   // scales
        out[(size_t)BATCH * 169 + BATCH + b] = sums[22];  // offsets (yy)
    }
}

extern "C" void kernel_launch(void* const* d_in, const int* in_sizes, int n_in,
                              void* d_out, int out_size, void* d_ws, size_t ws_size,
                              hipStream_t stream) {
    const float* m = (const float*)d_in[0];  // keypoints_3D_src (B,3,N)
    const float* y = (const float*)d_in[1];  // keypoints_3D_trg (B,3,N)
    const float* w = (const float*)d_in[2];  // weights (B,1,N)
    float* out = (float*)d_out;
    locblock_fused<<<BATCH, THREADS, 0, stream>>>(m, y, w, out);
}